// Round 1
// 290.006 us; speedup vs baseline: 1.0479x; 1.0479x over previous
//
#include <hip/hip_runtime.h>
#include <math.h>

// Fused Conv3d(3->16, k=3, valid) + bias + min over D + softmax over C.
// N=16, CIN=3, COUT=16, K=3, D=H=W=64 -> out [16,16,62,62] fp32.
//
// R4: R3 compute structure, but staging rebuilt as double-buffered
// global_load_lds DMA with hoisted address math and ONE barrier per chunk.
// The old stage->barrier->compute->barrier loop serialized a cold HBM
// round-trip per chunk (VALUBusy 61%, 39% idle). Now chunk c+1's DMA is
// issued right after the barrier and flies during chunk c's compute; the
// vmcnt(0) drain folded into __syncthreads then costs ~nothing.
// Staging LDS destinations were already lane-linear (F*16B), which is
// exactly what global_load_lds requires (wave-uniform base + lane*16).

#define CH 8  // d-slices per staged chunk

// apply taps (o,kh) for current (ci, row): 3 kw x 4 p x 3 kd FMAs
#define TAPS(o, kh)                                                        \
    _Pragma("unroll")                                                      \
    for (int kw = 0; kw < 3; ++kw) {                                       \
        const float wk0 = wreg[ci * 27 + 0  + (kh) * 3 + kw];              \
        const float wk1 = wreg[ci * 27 + 9  + (kh) * 3 + kw];              \
        const float wk2 = wreg[ci * 27 + 18 + (kh) * 3 + kw];              \
        _Pragma("unroll")                                                  \
        for (int p = 0; p < 4; ++p) {                                      \
            const float xv = row[kw + p];                                  \
            A2[o][p] = fmaf(xv, wk0, A2[o][p]); /* d' = d   */             \
            A1[o][p] = fmaf(xv, wk1, A1[o][p]); /* d' = d-1 */             \
            A0[o][p] = fmaf(xv, wk2, A0[o][p]); /* d' = d-2 */             \
        }                                                                  \
    }

__global__ __launch_bounds__(256) void conv3d_min_softmax(
    const float* __restrict__ x,     // [16,3,64,64,64]
    const float* __restrict__ wgt,   // [16,3,3,3,3]
    const float* __restrict__ bias,  // [16]
    float* __restrict__ out)         // [16,16,62,62]
{
    const int tid = threadIdx.x;
    const int co  = tid & 15;          // output channel on lane bits 0..3
    const int s   = tid >> 4;          // 0..15 strip id
    const int hh  = (s >> 2) * 2;      // output rows hh, hh+1 (0,2,4,6)
    const int ww  = (s & 3) * 4;       // output cols ww..ww+3 (0,4,8,12)
    const int n   = blockIdx.z;
    const int h0  = blockIdx.y * 8;    // 8 h-tiles cover rows 0..63 (62 valid)
    const int w0  = blockIdx.x * 16;   // 4 w-tiles cover cols 0..63 (62 valid)

    // staged x, double-buffered. Logical layout per buffer:
    // [3 ci][CH dd][10 rows][20 cols] = 4800 floats (19200 B), padded to
    // 1280 float4 (20480 B) so every thread issues exactly 5 DMAs.
    __shared__ __align__(16) float sx[2][1280 * 4];

    // per-thread weights: idx = ci*27 + kd*9 + kh*3 + kw
    float wreg[81];
#pragma unroll
    for (int i = 0; i < 81; ++i) wreg[i] = wgt[co * 81 + i];

    // ---- hoisted staging address math (chunk 0, d0 = 0) ----
    // float4 slot F = tid + 256*k maps to LDS byte offset F*16 (lane-linear)
    // and global float index (((ci*64 + dd)*64 + gh)*64 + gw).
    int goff[5];  // global BYTE offsets for k = 0..4
#pragma unroll
    for (int k = 0; k < 5; ++k) {
        int F  = tid + 256 * k;
        int Fc = F < 1200 ? F : 1199;    // pad region: harmless dup fetch
        int rowid = Fc / 5;              // ci*(CH*10) + dd*10 + r
        int g     = Fc - rowid * 5;      // col group (4 floats)
        int ci    = rowid / (CH * 10);
        int rem   = rowid - ci * (CH * 10);
        int dd    = rem / 10;
        int r     = rem - dd * 10;
        int gh    = min(h0 + r, 63);     // clamp: edge halo, unused
        int gw    = min(w0 + g * 4, 60); // clamp: cols >=62 unused
        goff[k]   = (((ci * 64 + dd) * 64 + gh) * 64 + gw) * 4;
    }
    const char* xb = (const char*)(x + (size_t)n * 3 * 64 * 64 * 64);
    char* const lds0 = (char*)&sx[0][0] + tid * 16;
    char* const lds1 = (char*)&sx[1][0] + tid * 16;

    // ring: A0 completes this step (kd=2), A1 next (kd=1), A2 after (kd=0)
    float A0[2][4], A1[2][4], A2[2][4], mv[2][4];
#pragma unroll
    for (int o = 0; o < 2; ++o)
#pragma unroll
        for (int p = 0; p < 4; ++p) {
            A0[o][p] = A1[o][p] = A2[o][p] = 0.f;
            mv[o][p] = 1e30f;
        }

    // ---- issue chunk 0 DMA ----
#pragma unroll
    for (int k = 0; k < 5; ++k)
        __builtin_amdgcn_global_load_lds(
            (const void*)(xb + goff[k]), (void*)(lds0 + k * 4096), 16, 0, 0);

    for (int c = 0; c < 64 / CH; ++c) {
        // Drains vmcnt(0): chunk c's DMA has landed; and all waves are done
        // reading buf[(c+1)&1] (their chunk c-1 compute), so it is free to
        // be overwritten by the prefetch below.
        __syncthreads();

        // ---- issue chunk c+1 DMA; flies during this chunk's compute ----
        if (c < 7) {
            const char* xc = xb + (size_t)(c + 1) * (CH * 64 * 64 * 4);
            char* ldsn = ((c + 1) & 1) ? lds1 : lds0;
#pragma unroll
            for (int k = 0; k < 5; ++k)
                __builtin_amdgcn_global_load_lds(
                    (const void*)(xc + goff[k]), (void*)(ldsn + k * 4096),
                    16, 0, 0);
        }

        const float* S = sx[c & 1];
        const int d0 = c * CH;

        // ---- compute CH d-steps from LDS ----
#pragma unroll 2
        for (int dd = 0; dd < CH; ++dd) {
#pragma unroll
            for (int ci = 0; ci < 3; ++ci) {
#pragma unroll
                for (int r = 0; r < 4; ++r) {
                    const int base = (ci * (CH * 10) + dd * 10 + hh + r) * 20 + ww;
                    const float4 a = *(const float4*)&S[base];
                    const float2 b = *(const float2*)&S[base + 4];
                    const float row[6] = {a.x, a.y, a.z, a.w, b.x, b.y};
                    if (r == 0) { TAPS(0, 0) }
                    if (r == 1) { TAPS(0, 1) TAPS(1, 0) }
                    if (r == 2) { TAPS(0, 2) TAPS(1, 1) }
                    if (r == 3) { TAPS(1, 2) }
                }
            }
            const int d = d0 + dd;
            if (d >= 2) {
#pragma unroll
                for (int o = 0; o < 2; ++o)
#pragma unroll
                    for (int p = 0; p < 4; ++p)
                        mv[o][p] = fminf(mv[o][p], A0[o][p]);
            }
#pragma unroll
            for (int o = 0; o < 2; ++o)
#pragma unroll
                for (int p = 0; p < 4; ++p) {
                    A0[o][p] = A1[o][p];
                    A1[o][p] = A2[o][p];
                    A2[o][p] = 0.f;
                }
        }
    }

    // ---- epilogue: bias, softmax over 16 channels (lanes), store ----
    const float bv = bias[co];
#pragma unroll
    for (int o = 0; o < 2; ++o) {
        const int hp = h0 + hh + o;
#pragma unroll
        for (int p = 0; p < 4; ++p) {
            float v = mv[o][p] + bv;
            float mx = v;
#pragma unroll
            for (int off = 1; off < 16; off <<= 1)
                mx = fmaxf(mx, __shfl_xor(mx, off, 64));
            float e = __expf(v - mx);
            float sum = e;
#pragma unroll
            for (int off = 1; off < 16; off <<= 1)
                sum += __shfl_xor(sum, off, 64);
            const int wp = w0 + ww + p;
            if (hp < 62 && wp < 62)
                out[(((size_t)n * 16 + co) * 62 + hp) * 62 + wp] = e / sum;
        }
    }
}

extern "C" void kernel_launch(void* const* d_in, const int* in_sizes, int n_in,
                              void* d_out, int out_size, void* d_ws, size_t ws_size,
                              hipStream_t stream) {
    const float* x    = (const float*)d_in[0];
    const float* wgt  = (const float*)d_in[1];
    const float* bias = (const float*)d_in[2];
    float* out        = (float*)d_out;
    dim3 grid(4, 8, 16);   // (w-tiles, h-tiles, n)
    dim3 block(256);
    hipLaunchKernelGGL(conv3d_min_softmax, grid, block, 0, stream,
                       x, wgt, bias, out);
}